// Round 3
// baseline (636.540 us; speedup 1.0000x reference)
//
#include <hip/hip_runtime.h>

#define BATCH 256
#define TT 4096
#define NS 32
#define NI 8
#define NO 8
#define LCH 64
#define NCHUNKS 64  // TT / LCH

// ws layout (floats)
#define WS_M  0
#define WS_N0 1024
#define WS_N1 1280
#define WS_ML 1536
#define WS_V  2560
#define WS_S  (2560 + BATCH * NCHUNKS * NS)
#define WS_F  (WS_S + BATCH * NCHUNKS * NS)  // [LCH+1][NS][NI]

__device__ __forceinline__ float dot4(float4 a, float4 b) {
    return a.x * b.x + a.y * b.y + a.z * b.z + a.w * b.w;
}
__device__ __forceinline__ float4 ld4(const float* p) { return *(const float4*)p; }

// ---------------------------------------------------------------------------
// Kernel 0: build step matrices M, N0, N1 (one Dopri5 step == x' = M x + N0 u0 + N1 u1),
// ML = M^64 for chunk propagation, and the convolution kernels
//   F_64 = N1 ; F_63 = N0 + M*N1 ; F_{j-1} = M * F_j
// so that v[b][c] = sum_{j=0..64} F_j u_{t0+j}. Single block, 256 threads.
// ---------------------------------------------------------------------------
__global__ __launch_bounds__(256) void k_pre(const float* __restrict__ tarr,
                                             const float* __restrict__ A,
                                             const float* __restrict__ B,
                                             float* __restrict__ ws) {
    __shared__ float sA[NS * NS], sB[NS * NI];
    __shared__ float Ka[6][NS * NS];
    __shared__ float Kb[6][NS * NI];
    __shared__ float Kc[6][NS * NI];
    __shared__ float Sa[NS * NS], Sb[NS * NI], Sc[NS * NI];
    __shared__ float Pq[2][NS * NS];
    __shared__ float Ms[NS * NS];
    __shared__ float Ff[2][NS * NI];

    const int tid = threadIdx.x;
    const float dt = tarr[1] - tarr[0];

    for (int e = tid; e < NS * NS; e += 256) sA[e] = A[e];
    for (int e = tid; e < NS * NI; e += 256) sB[e] = B[e];
    __syncthreads();
    for (int e = tid; e < NS * NS; e += 256) Ka[0][e] = sA[e];
    for (int e = tid; e < NS * NI; e += 256) { Kb[0][e] = sB[e]; Kc[0][e] = 0.f; }
    __syncthreads();

    const float atab[5][5] = {
        {0.2f, 0.f, 0.f, 0.f, 0.f},
        {3.f / 40.f, 9.f / 40.f, 0.f, 0.f, 0.f},
        {44.f / 45.f, -56.f / 15.f, 32.f / 9.f, 0.f, 0.f},
        {19372.f / 6561.f, -25360.f / 2187.f, 64448.f / 6561.f, -212.f / 729.f, 0.f},
        {9017.f / 3168.f, -355.f / 33.f, 46732.f / 5247.f, 49.f / 176.f, -5103.f / 18656.f}};
    const float ctab[6] = {0.f, 0.2f, 0.3f, 0.8f, 8.f / 9.f, 1.f};

    for (int st = 1; st <= 5; ++st) {
        for (int e = tid; e < NS * NS; e += 256) {
            float acc = 0.f;
            for (int j = 0; j < st; ++j) acc += atab[st - 1][j] * Ka[j][e];
            Sa[e] = acc;
        }
        for (int e = tid; e < NS * NI; e += 256) {
            float ab = 0.f, ac = 0.f;
            for (int j = 0; j < st; ++j) {
                ab += atab[st - 1][j] * Kb[j][e];
                ac += atab[st - 1][j] * Kc[j][e];
            }
            Sb[e] = ab; Sc[e] = ac;
        }
        __syncthreads();
        {
            const int j = tid & 31, ig = tid >> 5;
            for (int r = 0; r < 4; ++r) {
                const int row = ig + 8 * r;
                float acc = 0.f;
                for (int k = 0; k < NS; ++k) acc += sA[row * NS + k] * Sa[k * NS + j];
                Ka[st][row * NS + j] = sA[row * NS + j] + dt * acc;
            }
            const int jb = tid & 7, rb = tid >> 3;
            float ab = 0.f, ac = 0.f;
            for (int k = 0; k < NS; ++k) {
                ab += sA[rb * NS + k] * Sb[k * NI + jb];
                ac += sA[rb * NS + k] * Sc[k * NI + jb];
            }
            Kb[st][rb * NI + jb] = sB[rb * NI + jb] + dt * ab;
            Kc[st][rb * NI + jb] = ctab[st] * sB[rb * NI + jb] + dt * ac;
        }
        __syncthreads();
    }

    const float btab[6] = {35.f / 384.f, 0.f, 500.f / 1113.f, 125.f / 192.f,
                           -2187.f / 6784.f, 11.f / 84.f};
    for (int e = tid; e < NS * NS; e += 256) {
        float acc = 0.f;
        for (int i2 = 0; i2 < 6; ++i2) acc += btab[i2] * Ka[i2][e];
        const float m = dt * acc + (((e / NS) == (e % NS)) ? 1.f : 0.f);
        ws[WS_M + e] = m;
        Pq[0][e] = m;
        Ms[e] = m;  // keep a live copy of M for the F chain
    }
    for (int e = tid; e < NS * NI; e += 256) {
        float ap = 0.f, aq = 0.f;
        for (int i2 = 0; i2 < 6; ++i2) {
            ap += btab[i2] * Kb[i2][e];
            aq += btab[i2] * Kc[i2][e];
        }
        const float P = dt * ap, Q = dt * aq;
        ws[WS_N0 + e] = P - Q;  // coefficient of u_n
        ws[WS_N1 + e] = Q;      // coefficient of u_{n+1}
        Sb[e] = P - Q;          // reuse stage scratch: N0'
        Sc[e] = Q;              // N1'
    }
    __syncthreads();

    // ML = M^64 via 6 squarings
    int cur = 0;
    for (int itq = 0; itq < 6; ++itq) {
        const int j = tid & 31, ig = tid >> 5;
        for (int r = 0; r < 4; ++r) {
            const int row = ig + 8 * r;
            float acc = 0.f;
            for (int k = 0; k < NS; ++k) acc += Pq[cur][row * NS + k] * Pq[cur][k * NS + j];
            Pq[cur ^ 1][row * NS + j] = acc;
        }
        __syncthreads();
        cur ^= 1;
    }
    for (int e = tid; e < NS * NS; e += 256) ws[WS_ML + e] = Pq[cur][e];

    // F chain: F_64 = N1'; F_63 = N0' + M F_64; F_{j-1} = M F_j.
    // 256 threads == NS*NI elements, one element per thread, double-buffered LDS.
    Ff[0][tid] = Sc[tid];
    ws[WS_F + 64 * NS * NI + tid] = Sc[tid];
    __syncthreads();
    int fc = 0;
    const int rr = tid >> 3, mm = tid & 7;
    for (int j = 63; j >= 0; --j) {
        float acc = 0.f;
#pragma unroll
        for (int k = 0; k < NS; ++k) acc += Ms[rr * NS + k] * Ff[fc][k * NI + mm];
        if (j == 63) acc += Sb[tid];
        Ff[fc ^ 1][tid] = acc;
        ws[WS_F + j * NS * NI + tid] = acc;
        __syncthreads();
        fc ^= 1;
    }
}

// ---------------------------------------------------------------------------
// Phase 1 (GEMM form, v2): per (batch, chunk c<63)
//   v[b][c] = sum_{j=0..64} F_j u_{t0+j}
// 2 waves/block split the j-range (0..31 / 32..64); partials reduced via LDS.
// Explicit 2-stage software pipeline (A/B register buffers, no copies) so 10
// loads are always in flight; __launch_bounds__(128,4) raises the VGPR cap to
// 128 (round-1 version was register-starved at 44 VGPRs -> no MLP, 127 us).
// ---------------------------------------------------------------------------
__global__ __launch_bounds__(128, 4) void k_phase1(const float* __restrict__ u,
                                                   float* __restrict__ ws) {
    const int task = blockIdx.x;
    const int c = task % (NCHUNKS - 1), g = task / (NCHUNKS - 1);
    const int tid = threadIdx.x;
    const int h = tid >> 6, l = tid & 63;
    const int beta = l >> 3, s8 = l & 7;
    const int b = g * 8 + beta;
    const int t0 = c * LCH;
    const float* ub = u + ((size_t)b * TT + t0) * NI;
    // lane's F slice for step j: rows 4*s8..4*s8+3 == 32 consecutive floats
    const float* Fs = ws + WS_F + 32 * s8;
    const int j0 = h ? 32 : 0;
    const int j1 = h ? (LCH + 1) : 32;

    float4 Aq[10], Bq[10];  // [0..7]=F rows, [8..9]=u
    float a0 = 0.f, a1 = 0.f, a2 = 0.f, a3 = 0.f;

    {   // prologue: stage A <- j0
        const float* Fj = Fs + j0 * (NS * NI);
#pragma unroll
        for (int q = 0; q < 8; ++q) Aq[q] = ld4(Fj + 4 * q);
        Aq[8] = ld4(ub + j0 * NI);
        Aq[9] = ld4(ub + j0 * NI + 4);
    }

    for (int jj = j0; jj < j1; jj += 2) {
        if (jj + 1 < j1) {  // issue loads for jj+1 into B (uniform branch)
            const float* Fj = Fs + (jj + 1) * (NS * NI);
#pragma unroll
            for (int q = 0; q < 8; ++q) Bq[q] = ld4(Fj + 4 * q);
            Bq[8] = ld4(ub + (jj + 1) * NI);
            Bq[9] = ld4(ub + (jj + 1) * NI + 4);
        }
        a0 += dot4(Aq[0], Aq[8]) + dot4(Aq[1], Aq[9]);
        a1 += dot4(Aq[2], Aq[8]) + dot4(Aq[3], Aq[9]);
        a2 += dot4(Aq[4], Aq[8]) + dot4(Aq[5], Aq[9]);
        a3 += dot4(Aq[6], Aq[8]) + dot4(Aq[7], Aq[9]);
        if (jj + 2 < j1) {  // issue loads for jj+2 into A
            const float* Fj = Fs + (jj + 2) * (NS * NI);
#pragma unroll
            for (int q = 0; q < 8; ++q) Aq[q] = ld4(Fj + 4 * q);
            Aq[8] = ld4(ub + (jj + 2) * NI);
            Aq[9] = ld4(ub + (jj + 2) * NI + 4);
        }
        if (jj + 1 < j1) {
            a0 += dot4(Bq[0], Bq[8]) + dot4(Bq[1], Bq[9]);
            a1 += dot4(Bq[2], Bq[8]) + dot4(Bq[3], Bq[9]);
            a2 += dot4(Bq[4], Bq[8]) + dot4(Bq[5], Bq[9]);
            a3 += dot4(Bq[6], Bq[8]) + dot4(Bq[7], Bq[9]);
        }
    }

    // cross-wave reduce of the two j-half partials
    __shared__ float4 red[64];
    if (h == 1) red[l] = make_float4(a0, a1, a2, a3);
    __syncthreads();
    if (h == 0) {
        const float4 o = red[l];
        *(float4*)(ws + WS_V + ((size_t)b * NCHUNKS + c) * NS + 4 * s8) =
            make_float4(a0 + o.x, a1 + o.y, a2 + o.z, a3 + o.w);
    }
}

// ---------------------------------------------------------------------------
// Phase 2: propagate chunk start states. One wave per batch.
//   s[b][0] = x0[b];  s[b][c+1] = ML s[b][c] + v[b][c]
// ---------------------------------------------------------------------------
__global__ __launch_bounds__(64) void k_phase2(const float* __restrict__ x0,
                                               float* __restrict__ ws) {
    const float* ML = ws + WS_ML;
    const float* v = ws + WS_V;
    float* sst = ws + WS_S;
    const int b = blockIdx.x;
    const int l = threadIdx.x, i = l & 31, h = l >> 5;

    float mlr[16];
#pragma unroll
    for (int jj = 0; jj < 16; ++jj) mlr[jj] = ML[i * NS + 16 * h + jj];

    float x = x0[b * NS + i];
    for (int c = 0; c < NCHUNKS; ++c) {
        if (h == 0) sst[((size_t)b * NCHUNKS + c) * NS + i] = x;
        if (c == NCHUNKS - 1) break;
        float p = 0.f;
#pragma unroll
        for (int jj = 0; jj < 16; ++jj) p += mlr[jj] * __shfl(x, 16 * h + jj, 64);
        p += __shfl_xor(p, 32, 64);
        x = p + v[((size_t)b * NCHUNKS + c) * NS + i];
    }
}

// ---------------------------------------------------------------------------
// Phase 3: replay chunks from true start states, writing xs and ys (fused).
// Single-wave workgroups => wave-synchronous: NO __syncthreads (which would
// drain vmcnt(0) each step, serializing the u loads and xs/y stores onto the
// serial chain). LDS x-exchange is ordered with an explicit lgkmcnt(0) wait.
// u is prefetched two steps ahead so global latency is off the chain.
// ---------------------------------------------------------------------------
__global__ __launch_bounds__(64, 1) void k_phase3(const float* __restrict__ u,
                                                  float* __restrict__ ws,
                                                  float* __restrict__ out,
                                                  const float* __restrict__ Cc,
                                                  const float* __restrict__ Dd) {
    const float* M = ws + WS_M;
    const float* N0 = ws + WS_N0;
    const float* N1 = ws + WS_N1;

    const int task = blockIdx.x;
    const int c = task % NCHUNKS, g = task / NCHUNKS;
    const int l = threadIdx.x;
    const int beta = l >> 3, s8 = l & 7;
    const int b = g * 8 + beta;

    // cache M rows 4*s8 .. 4*s8+3 (128 VGPRs)
    float4 mq[4][8];
#pragma unroll
    for (int r = 0; r < 4; ++r)
#pragma unroll
        for (int jj = 0; jj < 8; ++jj) mq[r][jj] = ld4(M + (4 * s8 + r) * NS + 4 * jj);

    float4 n0q[4][2], n1q[4][2];
#pragma unroll
    for (int r = 0; r < 4; ++r) {
        n0q[r][0] = ld4(N0 + (4 * s8 + r) * NI);
        n0q[r][1] = ld4(N0 + (4 * s8 + r) * NI + 4);
        n1q[r][0] = ld4(N1 + (4 * s8 + r) * NI);
        n1q[r][1] = ld4(N1 + (4 * s8 + r) * NI + 4);
    }

    float4 cq[8], dq[2];
#pragma unroll
    for (int jj = 0; jj < 8; ++jj) cq[jj] = ld4(Cc + s8 * NS + 4 * jj);
    dq[0] = ld4(Dd + s8 * NI);
    dq[1] = ld4(Dd + s8 * NI + 4);

    // per-wave x buffer, double-buffered; row stride 9 float4 so the 8-batch
    // b128 reads at fixed jj hit 8 distinct 4-bank groups (conflict-free).
    __shared__ float4 xb[2][8 * 9];

    const int t0 = c * LCH;
    const float* ub = u + (size_t)b * TT * NI;
    float4 u0a = ld4(ub + t0 * NI), u0b = ld4(ub + t0 * NI + 4);
    float4 u1a = ld4(ub + (t0 + 1) * NI), u1b = ld4(ub + (t0 + 1) * NI + 4);

    float4 mine = ld4(ws + WS_S + ((size_t)b * NCHUNKS + c) * NS + 4 * s8);
    xb[0][beta * 9 + s8] = mine;
    asm volatile("s_waitcnt lgkmcnt(0)" ::: "memory");
    __builtin_amdgcn_sched_barrier(0);

    float* yout = out + (size_t)BATCH * TT * NS;
    int cur = 0;
    for (int js = 0; js < LCH; ++js) {
        const int t = t0 + js;
        float4 xq[8];
#pragma unroll
        for (int jj = 0; jj < 8; ++jj) xq[jj] = xb[cur][beta * 9 + jj];

        // prefetch u[t+2] (becomes u1 next iteration); clamp keeps it in-bounds,
        // redundant values on the last two steps are never consumed.
        const int tp = (t + 2 < TT - 1) ? (t + 2) : (TT - 1);
        const float4 u2a = ld4(ub + tp * NI);
        const float4 u2b = ld4(ub + tp * NI + 4);

        // store xs[b][t][4*s8 .. 4*s8+3] (value held from prev step / init)
        *(float4*)(out + ((size_t)b * TT + t) * NS + 4 * s8) = mine;
        // y[b][t][o], o == s8
        float yv = 0.f;
#pragma unroll
        for (int jj = 0; jj < 8; ++jj) yv += dot4(cq[jj], xq[jj]);
        yv += dot4(dq[0], u0a) + dot4(dq[1], u0b);
        yout[((size_t)b * TT + t) * NO + s8] = yv;

        if (js < LCH - 1) {
            float w0 = dot4(n0q[0][0], u0a) + dot4(n0q[0][1], u0b) + dot4(n1q[0][0], u1a) + dot4(n1q[0][1], u1b);
            float w1 = dot4(n0q[1][0], u0a) + dot4(n0q[1][1], u0b) + dot4(n1q[1][0], u1a) + dot4(n1q[1][1], u1b);
            float w2 = dot4(n0q[2][0], u0a) + dot4(n0q[2][1], u0b) + dot4(n1q[2][0], u1a) + dot4(n1q[2][1], u1b);
            float w3 = dot4(n0q[3][0], u0a) + dot4(n0q[3][1], u0b) + dot4(n1q[3][0], u1a) + dot4(n1q[3][1], u1b);
#pragma unroll
            for (int jj = 0; jj < 8; ++jj) {
                const float4 xv = xq[jj];
                w0 += dot4(mq[0][jj], xv);
                w1 += dot4(mq[1][jj], xv);
                w2 += dot4(mq[2][jj], xv);
                w3 += dot4(mq[3][jj], xv);
            }
            mine = make_float4(w0, w1, w2, w3);
            xb[cur ^ 1][beta * 9 + s8] = mine;
            u0a = u1a; u0b = u1b;
            u1a = u2a; u1b = u2b;
        }
        asm volatile("s_waitcnt lgkmcnt(0)" ::: "memory");
        __builtin_amdgcn_sched_barrier(0);
        cur ^= 1;
    }
}

extern "C" void kernel_launch(void* const* d_in, const int* in_sizes, int n_in,
                              void* d_out, int out_size, void* d_ws, size_t ws_size,
                              hipStream_t stream) {
    const float* t = (const float*)d_in[0];
    const float* u = (const float*)d_in[1];
    const float* x0 = (const float*)d_in[2];
    const float* A = (const float*)d_in[3];
    const float* B = (const float*)d_in[4];
    const float* C = (const float*)d_in[5];
    const float* D = (const float*)d_in[6];
    float* out = (float*)d_out;
    float* ws = (float*)d_ws;

    k_pre<<<dim3(1), dim3(256), 0, stream>>>(t, A, B, ws);
    k_phase1<<<dim3(32 * (NCHUNKS - 1)), dim3(128), 0, stream>>>(u, ws);
    k_phase2<<<dim3(BATCH), dim3(64), 0, stream>>>(x0, ws);
    k_phase3<<<dim3(32 * NCHUNKS), dim3(64), 0, stream>>>(u, ws, out, C, D);
}

// Round 4
// 353.338 us; speedup vs baseline: 1.8015x; 1.8015x over previous
//
#include <hip/hip_runtime.h>

#define BATCH 256
#define TT 4096
#define NS 32
#define NI 8
#define NO 8
#define LCH 64
#define NCHUNKS 64  // TT / LCH

// ws layout (floats)
#define WS_M  0
#define WS_N0 1024
#define WS_N1 1280
#define WS_ML 1536
#define WS_V  2560
#define WS_S  (2560 + BATCH * NCHUNKS * NS)
#define WS_F  (WS_S + BATCH * NCHUNKS * NS)  // [LCH+1][NS][NI]

__device__ __forceinline__ float dot4(float4 a, float4 b) {
    return a.x * b.x + a.y * b.y + a.z * b.z + a.w * b.w;
}
__device__ __forceinline__ float4 ld4(const float* p) { return *(const float4*)p; }

// ---------------------------------------------------------------------------
// Kernel 0: build step matrices M, N0, N1 (one Dopri5 step == x' = M x + N0 u0 + N1 u1),
// ML = M^64 for chunk propagation, and the convolution kernels
//   F_64 = N1 ; F_63 = N0 + M*N1 ; F_{j-1} = M * F_j
// so that v[b][c] = sum_{j=0..64} F_j u_{t0+j}. Single block, 256 threads.
// ---------------------------------------------------------------------------
__global__ __launch_bounds__(256) void k_pre(const float* __restrict__ tarr,
                                             const float* __restrict__ A,
                                             const float* __restrict__ B,
                                             float* __restrict__ ws) {
    __shared__ float sA[NS * NS], sB[NS * NI];
    __shared__ float Ka[6][NS * NS];
    __shared__ float Kb[6][NS * NI];
    __shared__ float Kc[6][NS * NI];
    __shared__ float Sa[NS * NS], Sb[NS * NI], Sc[NS * NI];
    __shared__ float Pq[2][NS * NS];
    __shared__ float Ms[NS * NS];
    __shared__ float Ff[2][NS * NI];

    const int tid = threadIdx.x;
    const float dt = tarr[1] - tarr[0];

    for (int e = tid; e < NS * NS; e += 256) sA[e] = A[e];
    for (int e = tid; e < NS * NI; e += 256) sB[e] = B[e];
    __syncthreads();
    for (int e = tid; e < NS * NS; e += 256) Ka[0][e] = sA[e];
    for (int e = tid; e < NS * NI; e += 256) { Kb[0][e] = sB[e]; Kc[0][e] = 0.f; }
    __syncthreads();

    const float atab[5][5] = {
        {0.2f, 0.f, 0.f, 0.f, 0.f},
        {3.f / 40.f, 9.f / 40.f, 0.f, 0.f, 0.f},
        {44.f / 45.f, -56.f / 15.f, 32.f / 9.f, 0.f, 0.f},
        {19372.f / 6561.f, -25360.f / 2187.f, 64448.f / 6561.f, -212.f / 729.f, 0.f},
        {9017.f / 3168.f, -355.f / 33.f, 46732.f / 5247.f, 49.f / 176.f, -5103.f / 18656.f}};
    const float ctab[6] = {0.f, 0.2f, 0.3f, 0.8f, 8.f / 9.f, 1.f};

    for (int st = 1; st <= 5; ++st) {
        for (int e = tid; e < NS * NS; e += 256) {
            float acc = 0.f;
            for (int j = 0; j < st; ++j) acc += atab[st - 1][j] * Ka[j][e];
            Sa[e] = acc;
        }
        for (int e = tid; e < NS * NI; e += 256) {
            float ab = 0.f, ac = 0.f;
            for (int j = 0; j < st; ++j) {
                ab += atab[st - 1][j] * Kb[j][e];
                ac += atab[st - 1][j] * Kc[j][e];
            }
            Sb[e] = ab; Sc[e] = ac;
        }
        __syncthreads();
        {
            const int j = tid & 31, ig = tid >> 5;
            for (int r = 0; r < 4; ++r) {
                const int row = ig + 8 * r;
                float acc = 0.f;
                for (int k = 0; k < NS; ++k) acc += sA[row * NS + k] * Sa[k * NS + j];
                Ka[st][row * NS + j] = sA[row * NS + j] + dt * acc;
            }
            const int jb = tid & 7, rb = tid >> 3;
            float ab = 0.f, ac = 0.f;
            for (int k = 0; k < NS; ++k) {
                ab += sA[rb * NS + k] * Sb[k * NI + jb];
                ac += sA[rb * NS + k] * Sc[k * NI + jb];
            }
            Kb[st][rb * NI + jb] = sB[rb * NI + jb] + dt * ab;
            Kc[st][rb * NI + jb] = ctab[st] * sB[rb * NI + jb] + dt * ac;
        }
        __syncthreads();
    }

    const float btab[6] = {35.f / 384.f, 0.f, 500.f / 1113.f, 125.f / 192.f,
                           -2187.f / 6784.f, 11.f / 84.f};
    for (int e = tid; e < NS * NS; e += 256) {
        float acc = 0.f;
        for (int i2 = 0; i2 < 6; ++i2) acc += btab[i2] * Ka[i2][e];
        const float m = dt * acc + (((e / NS) == (e % NS)) ? 1.f : 0.f);
        ws[WS_M + e] = m;
        Pq[0][e] = m;
        Ms[e] = m;  // keep a live copy of M for the F chain
    }
    for (int e = tid; e < NS * NI; e += 256) {
        float ap = 0.f, aq = 0.f;
        for (int i2 = 0; i2 < 6; ++i2) {
            ap += btab[i2] * Kb[i2][e];
            aq += btab[i2] * Kc[i2][e];
        }
        const float P = dt * ap, Q = dt * aq;
        ws[WS_N0 + e] = P - Q;  // coefficient of u_n
        ws[WS_N1 + e] = Q;      // coefficient of u_{n+1}
        Sb[e] = P - Q;          // reuse stage scratch: N0'
        Sc[e] = Q;              // N1'
    }
    __syncthreads();

    // ML = M^64 via 6 squarings
    int cur = 0;
    for (int itq = 0; itq < 6; ++itq) {
        const int j = tid & 31, ig = tid >> 5;
        for (int r = 0; r < 4; ++r) {
            const int row = ig + 8 * r;
            float acc = 0.f;
            for (int k = 0; k < NS; ++k) acc += Pq[cur][row * NS + k] * Pq[cur][k * NS + j];
            Pq[cur ^ 1][row * NS + j] = acc;
        }
        __syncthreads();
        cur ^= 1;
    }
    for (int e = tid; e < NS * NS; e += 256) ws[WS_ML + e] = Pq[cur][e];

    // F chain: F_64 = N1'; F_63 = N0' + M F_64; F_{j-1} = M F_j.
    // 256 threads == NS*NI elements, one element per thread, double-buffered LDS.
    Ff[0][tid] = Sc[tid];
    ws[WS_F + 64 * NS * NI + tid] = Sc[tid];
    __syncthreads();
    int fc = 0;
    const int rr = tid >> 3, mm = tid & 7;
    for (int j = 63; j >= 0; --j) {
        float acc = 0.f;
#pragma unroll
        for (int k = 0; k < NS; ++k) acc += Ms[rr * NS + k] * Ff[fc][k * NI + mm];
        if (j == 63) acc += Sb[tid];
        Ff[fc ^ 1][tid] = acc;
        ws[WS_F + j * NS * NI + tid] = acc;
        __syncthreads();
        fc ^= 1;
    }
}

// ---------------------------------------------------------------------------
// Phase 1 (GEMM form, v3): per (batch, chunk c<63)
//   v[b][c] = sum_{j=0..64} F_j u_{t0+j}
// v2 failed: 2-deep register pipeline (20 float4 live) vs 64-VGPR allocation
// -> spilled to scratch (689 MB writes, 310 us). v3 stages F[0..63] in LDS
// (exactly 64 KB), TRANSPOSED to sF[j][q][s8] so each lane's b128 read lands
// in bank-group s8 (conflict-free; naive layout is an 8-way conflict).
// 256 threads = 4 waves = 4 tasks per block; register demand ~30 VGPRs.
// j=64 tail (F_64 = N1) is applied from global after the loop.
// ---------------------------------------------------------------------------
__global__ __launch_bounds__(256, 2) void k_phase1(const float* __restrict__ u,
                                                   float* __restrict__ ws) {
    __shared__ float4 sF[64 * 64];  // [j][q][s8], 65536 B

    const int tid = threadIdx.x;

    // cooperative stage: global F4[j*64 + 8*s8r + q] -> sF[j*64 + q*8 + s8r]
    const float4* Fg = (const float4*)(ws + WS_F);
    for (int idx = tid; idx < 64 * 64; idx += 256) {
        const int j = idx >> 6, r = idx & 63;
        sF[(j << 6) + ((r & 7) << 3) + (r >> 3)] = Fg[idx];
    }
    __syncthreads();

    const int task = blockIdx.x * 4 + (tid >> 6);
    const int c = task % (NCHUNKS - 1), g = task / (NCHUNKS - 1);
    const int l = tid & 63;
    const int beta = l >> 3, s8 = l & 7;
    const int b = g * 8 + beta;
    const int t0 = c * LCH;
    const float* ub = u + ((size_t)b * TT + t0) * NI;

    float4 ua = ld4(ub), uc = ld4(ub + 4);
    float a0 = 0.f, a1 = 0.f, a2 = 0.f, a3 = 0.f;

#pragma unroll 4
    for (int j = 0; j < 64; ++j) {
        // prefetch next u (always valid: t0+64 <= 4032)
        const float4 na = ld4(ub + (j + 1) * NI);
        const float4 nb = ld4(ub + (j + 1) * NI + 4);
        const float4* fj = &sF[(j << 6) + s8];
        const float4 f0 = fj[0], f1 = fj[8], f2 = fj[16], f3 = fj[24];
        const float4 f4 = fj[32], f5 = fj[40], f6 = fj[48], f7 = fj[56];
        a0 += dot4(f0, ua) + dot4(f1, uc);
        a1 += dot4(f2, ua) + dot4(f3, uc);
        a2 += dot4(f4, ua) + dot4(f5, uc);
        a3 += dot4(f6, ua) + dot4(f7, uc);
        ua = na; uc = nb;
    }

    // j = 64 tail: F_64 rows from global (tiny, L2-resident)
    const float* Ft = ws + WS_F + 64 * (NS * NI) + 32 * s8;
    a0 += dot4(ld4(Ft), ua) + dot4(ld4(Ft + 4), uc);
    a1 += dot4(ld4(Ft + 8), ua) + dot4(ld4(Ft + 12), uc);
    a2 += dot4(ld4(Ft + 16), ua) + dot4(ld4(Ft + 20), uc);
    a3 += dot4(ld4(Ft + 24), ua) + dot4(ld4(Ft + 28), uc);

    *(float4*)(ws + WS_V + ((size_t)b * NCHUNKS + c) * NS + 4 * s8) =
        make_float4(a0, a1, a2, a3);
}

// ---------------------------------------------------------------------------
// Phase 2: propagate chunk start states. One wave per batch.
//   s[b][0] = x0[b];  s[b][c+1] = ML s[b][c] + v[b][c]
// ---------------------------------------------------------------------------
__global__ __launch_bounds__(64) void k_phase2(const float* __restrict__ x0,
                                               float* __restrict__ ws) {
    const float* ML = ws + WS_ML;
    const float* v = ws + WS_V;
    float* sst = ws + WS_S;
    const int b = blockIdx.x;
    const int l = threadIdx.x, i = l & 31, h = l >> 5;

    float mlr[16];
#pragma unroll
    for (int jj = 0; jj < 16; ++jj) mlr[jj] = ML[i * NS + 16 * h + jj];

    float x = x0[b * NS + i];
    for (int c = 0; c < NCHUNKS; ++c) {
        if (h == 0) sst[((size_t)b * NCHUNKS + c) * NS + i] = x;
        if (c == NCHUNKS - 1) break;
        float p = 0.f;
#pragma unroll
        for (int jj = 0; jj < 16; ++jj) p += mlr[jj] * __shfl(x, 16 * h + jj, 64);
        p += __shfl_xor(p, 32, 64);
        x = p + v[((size_t)b * NCHUNKS + c) * NS + i];
    }
}

// ---------------------------------------------------------------------------
// Phase 3: replay chunks from true start states, writing xs and ys (fused).
// Single-wave workgroups => wave-synchronous: NO __syncthreads (which would
// drain vmcnt(0) each step, serializing the u loads and xs/y stores onto the
// serial chain). LDS x-exchange is ordered with an explicit lgkmcnt(0) wait.
// u is prefetched two steps ahead so global latency is off the chain.
// ---------------------------------------------------------------------------
__global__ __launch_bounds__(64, 1) void k_phase3(const float* __restrict__ u,
                                                  float* __restrict__ ws,
                                                  float* __restrict__ out,
                                                  const float* __restrict__ Cc,
                                                  const float* __restrict__ Dd) {
    const float* M = ws + WS_M;
    const float* N0 = ws + WS_N0;
    const float* N1 = ws + WS_N1;

    const int task = blockIdx.x;
    const int c = task % NCHUNKS, g = task / NCHUNKS;
    const int l = threadIdx.x;
    const int beta = l >> 3, s8 = l & 7;
    const int b = g * 8 + beta;

    // cache M rows 4*s8 .. 4*s8+3 (128 VGPRs)
    float4 mq[4][8];
#pragma unroll
    for (int r = 0; r < 4; ++r)
#pragma unroll
        for (int jj = 0; jj < 8; ++jj) mq[r][jj] = ld4(M + (4 * s8 + r) * NS + 4 * jj);

    float4 n0q[4][2], n1q[4][2];
#pragma unroll
    for (int r = 0; r < 4; ++r) {
        n0q[r][0] = ld4(N0 + (4 * s8 + r) * NI);
        n0q[r][1] = ld4(N0 + (4 * s8 + r) * NI + 4);
        n1q[r][0] = ld4(N1 + (4 * s8 + r) * NI);
        n1q[r][1] = ld4(N1 + (4 * s8 + r) * NI + 4);
    }

    float4 cq[8], dq[2];
#pragma unroll
    for (int jj = 0; jj < 8; ++jj) cq[jj] = ld4(Cc + s8 * NS + 4 * jj);
    dq[0] = ld4(Dd + s8 * NI);
    dq[1] = ld4(Dd + s8 * NI + 4);

    // per-wave x buffer, double-buffered; row stride 9 float4 so the 8-batch
    // b128 reads at fixed jj hit 8 distinct 4-bank groups (conflict-free).
    __shared__ float4 xb[2][8 * 9];

    const int t0 = c * LCH;
    const float* ub = u + (size_t)b * TT * NI;
    float4 u0a = ld4(ub + t0 * NI), u0b = ld4(ub + t0 * NI + 4);
    float4 u1a = ld4(ub + (t0 + 1) * NI), u1b = ld4(ub + (t0 + 1) * NI + 4);

    float4 mine = ld4(ws + WS_S + ((size_t)b * NCHUNKS + c) * NS + 4 * s8);
    xb[0][beta * 9 + s8] = mine;
    asm volatile("s_waitcnt lgkmcnt(0)" ::: "memory");
    __builtin_amdgcn_sched_barrier(0);

    float* yout = out + (size_t)BATCH * TT * NS;
    int cur = 0;
    for (int js = 0; js < LCH; ++js) {
        const int t = t0 + js;
        float4 xq[8];
#pragma unroll
        for (int jj = 0; jj < 8; ++jj) xq[jj] = xb[cur][beta * 9 + jj];

        // prefetch u[t+2] (becomes u1 next iteration); clamp keeps it in-bounds,
        // redundant values on the last two steps are never consumed.
        const int tp = (t + 2 < TT - 1) ? (t + 2) : (TT - 1);
        const float4 u2a = ld4(ub + tp * NI);
        const float4 u2b = ld4(ub + tp * NI + 4);

        // store xs[b][t][4*s8 .. 4*s8+3] (value held from prev step / init)
        *(float4*)(out + ((size_t)b * TT + t) * NS + 4 * s8) = mine;
        // y[b][t][o], o == s8
        float yv = 0.f;
#pragma unroll
        for (int jj = 0; jj < 8; ++jj) yv += dot4(cq[jj], xq[jj]);
        yv += dot4(dq[0], u0a) + dot4(dq[1], u0b);
        yout[((size_t)b * TT + t) * NO + s8] = yv;

        if (js < LCH - 1) {
            float w0 = dot4(n0q[0][0], u0a) + dot4(n0q[0][1], u0b) + dot4(n1q[0][0], u1a) + dot4(n1q[0][1], u1b);
            float w1 = dot4(n0q[1][0], u0a) + dot4(n0q[1][1], u0b) + dot4(n1q[1][0], u1a) + dot4(n1q[1][1], u1b);
            float w2 = dot4(n0q[2][0], u0a) + dot4(n0q[2][1], u0b) + dot4(n1q[2][0], u1a) + dot4(n1q[2][1], u1b);
            float w3 = dot4(n0q[3][0], u0a) + dot4(n0q[3][1], u0b) + dot4(n1q[3][0], u1a) + dot4(n1q[3][1], u1b);
#pragma unroll
            for (int jj = 0; jj < 8; ++jj) {
                const float4 xv = xq[jj];
                w0 += dot4(mq[0][jj], xv);
                w1 += dot4(mq[1][jj], xv);
                w2 += dot4(mq[2][jj], xv);
                w3 += dot4(mq[3][jj], xv);
            }
            mine = make_float4(w0, w1, w2, w3);
            xb[cur ^ 1][beta * 9 + s8] = mine;
            u0a = u1a; u0b = u1b;
            u1a = u2a; u1b = u2b;
        }
        asm volatile("s_waitcnt lgkmcnt(0)" ::: "memory");
        __builtin_amdgcn_sched_barrier(0);
        cur ^= 1;
    }
}

extern "C" void kernel_launch(void* const* d_in, const int* in_sizes, int n_in,
                              void* d_out, int out_size, void* d_ws, size_t ws_size,
                              hipStream_t stream) {
    const float* t = (const float*)d_in[0];
    const float* u = (const float*)d_in[1];
    const float* x0 = (const float*)d_in[2];
    const float* A = (const float*)d_in[3];
    const float* B = (const float*)d_in[4];
    const float* C = (const float*)d_in[5];
    const float* D = (const float*)d_in[6];
    float* out = (float*)d_out;
    float* ws = (float*)d_ws;

    k_pre<<<dim3(1), dim3(256), 0, stream>>>(t, A, B, ws);
    k_phase1<<<dim3(8 * (NCHUNKS - 1)), dim3(256), 0, stream>>>(u, ws);
    k_phase2<<<dim3(BATCH), dim3(64), 0, stream>>>(x0, ws);
    k_phase3<<<dim3(32 * NCHUNKS), dim3(64), 0, stream>>>(u, ws, out, C, D);
}